// Round 7
// baseline (405.303 us; speedup 1.0000x reference)
//
#include <hip/hip_runtime.h>
#include <hip/hip_fp16.h>
#include <cstdint>

#define THREADS 256
#define NBLK 64     // blocks for hist/scatter
#define BPAD 512    // padded bucket count (dst>>8; N<=131072)

// ---------------- init ----------------
__global__ void init_kernel(float* pool, int* root, int G) {
  int i = blockIdx.x * blockDim.x + threadIdx.x;
  if (i < G * 64) pool[i] = 0.0f;
  if (i < G) root[i] = 0x7fffffff;
}

// ---------------- CSR build: bucket sort, no global atomics ----------------
__global__ __launch_bounds__(256) void hist_kernel(const int* __restrict__ dst_e,
                                                   int* __restrict__ hist, int E, int chunk) {
  __shared__ int hcnt[BPAD];
  int t = threadIdx.x, blk = blockIdx.x;
  for (int i = t; i < BPAD; i += 256) hcnt[i] = 0;
  __syncthreads();
  int s = blk * chunk, e = s + chunk;
  if (e > E) e = E;
  for (int i = s + t; i < e; i += 256) atomicAdd(&hcnt[dst_e[i] >> 8], 1);
  __syncthreads();
  for (int b = t; b < BPAD; b += 256) hist[b * NBLK + blk] = hcnt[b];
}

__global__ __launch_bounds__(256) void hscan_kernel(int* __restrict__ hist) {
  __shared__ int part[256];
  const int PER = (BPAD * NBLK) / 256;  // 128
  int t = threadIdx.x;
  int base = t * PER;
  int sum = 0;
  for (int k = 0; k < PER; k++) sum += hist[base + k];
  part[t] = sum;
  __syncthreads();
  int own = sum;
  for (int off = 1; off < 256; off <<= 1) {
    int v = (t >= off) ? part[t - off] : 0;
    __syncthreads();
    part[t] += v;
    __syncthreads();
  }
  int run = part[t] - own;
  for (int k = 0; k < PER; k++) {
    int h = hist[base + k];
    hist[base + k] = run;
    run += h;
  }
}

// scatter edges into bucket-partitioned ebuf, packed (src<<8)|(dst&255).
__global__ __launch_bounds__(256) void scatter_kernel(const int* __restrict__ src_e,
                                                      const int* __restrict__ dst_e,
                                                      const int* __restrict__ hist,
                                                      unsigned int* __restrict__ ebuf,
                                                      int E, int chunk) {
  __shared__ int cur[BPAD];
  int t = threadIdx.x, blk = blockIdx.x;
  for (int b = t; b < BPAD; b += 256) cur[b] = hist[b * NBLK + blk];
  __syncthreads();
  int s = blk * chunk, e = s + chunk;
  if (e > E) e = E;
  for (int i = s + t; i < e; i += 256) {
    int d = dst_e[i];
    unsigned int sv = (unsigned int)src_e[i];
    int slot = atomicAdd(&cur[d >> 8], 1);
    ebuf[slot] = (sv << 8) | (unsigned int)(d & 255);
  }
}

// per-bucket CSR finalize: row_start + csr_src + local-dst byte.
__global__ __launch_bounds__(256) void build_kernel(const unsigned int* __restrict__ ebuf,
                                                    const int* __restrict__ hist,
                                                    int* __restrict__ row_start,
                                                    int* __restrict__ csr_src,
                                                    unsigned char* __restrict__ dst8,
                                                    int N, int E) {
  __shared__ int counts[256];
  __shared__ int sc[256];
  __shared__ int curw[256];
  int t = threadIdx.x, b = blockIdx.x;
  int nbase = b * 256;
  int ebase = hist[b * NBLK];
  int eend = hist[(b + 1) * NBLK];
  counts[t] = 0;
  __syncthreads();
  int ecount = eend - ebase;
  for (int i = t; i < ecount; i += 256)
    atomicAdd(&counts[ebuf[ebase + i] & 255u], 1);
  __syncthreads();
  int n = nbase + t;
  int val = (n < N) ? counts[t] + 1 : 0;  // +1 self-loop
  sc[t] = val;
  __syncthreads();
  int own = val;
  for (int off = 1; off < 256; off <<= 1) {
    int v = (t >= off) ? sc[t - off] : 0;
    __syncthreads();
    sc[t] += v;
    __syncthreads();
  }
  int myloc = sc[t] - own;  // exclusive
  int rowb = ebase + nbase;  // prior real edges + prior self-loops
  if (n < N) {
    row_start[n] = rowb + myloc;
    csr_src[rowb + myloc + counts[t]] = n;  // self-loop in last slot
    dst8[rowb + myloc + counts[t]] = (unsigned char)t;
    if (n == N - 1) row_start[N] = rowb + myloc + counts[t] + 1;
  }
  curw[t] = rowb + myloc;
  __syncthreads();
  for (int i = t; i < ecount; i += 256) {
    unsigned int ev = ebuf[ebase + i];
    int ld = (int)(ev & 255u);
    int pos = atomicAdd(&curw[ld], 1);
    csr_src[pos] = (int)(ev >> 8);
    dst8[pos] = (unsigned char)ld;
  }
}

// ---------------- linear + attention scalars ----------------
// 8-node x 8-channel register tile per lane: wave covers 64 nodes x 64 ch.
// lane = no*8+co: no = node octet, co = channel octet. Per k: 8 broadcast
// ds_read_b32 (sIn, row pad 33 -> 2-way bank alias, free) + 2 ds_read_b128
// (sW) feed 64 FMAs -> VALU-bound, not LDS-bound.
template <int K>
__global__ __launch_bounds__(256) void lin_attn_kernel(
    const float* __restrict__ in, const float* __restrict__ W,
    const float* __restrict__ a_src, const float* __restrict__ a_dst,
    __half2* __restrict__ h2, float* __restrict__ as_, float* __restrict__ ad_, int N) {
  constexpr int CH = 32;                 // k-chunk
  constexpr int NCH = K / CH;
  __shared__ float sW[CH * 64];          // 8 KB
  __shared__ float sIn[256 * 33];        // 33.8 KB
  const int t = threadIdx.x;
  const int lane = t & 63, w = t >> 6;
  const int co = lane & 7, no = lane >> 3;
  const int blockBase = blockIdx.x * 256;

  float acc[8][8];
#pragma unroll
  for (int j = 0; j < 8; j++)
#pragma unroll
    for (int c = 0; c < 8; c++) acc[j][c] = 0.f;

  for (int kc = 0; kc < NCH; kc++) {
    // stage W chunk (coalesced float4)
    const float4* wv4 = (const float4*)(W + (size_t)kc * CH * 64);
    for (int i = t; i < CH * 16; i += 256) *(float4*)&sW[i * 4] = wv4[i];
    // stage input chunk: 256 nodes x CH floats (scalar LDS writes, padded rows)
    for (int i = t; i < 256 * (CH / 4); i += 256) {
      int nib = i >> 3;   // CH/4 = 8 float4 per node
      int off = i & 7;
      int node = blockBase + nib;
      float4 v = make_float4(0.f, 0.f, 0.f, 0.f);
      if (node < N) v = *(const float4*)&in[(size_t)node * K + kc * CH + off * 4];
      float* dst = &sIn[nib * 33 + off * 4];
      dst[0] = v.x; dst[1] = v.y; dst[2] = v.z; dst[3] = v.w;
    }
    __syncthreads();
#pragma unroll 4
    for (int k = 0; k < CH; k++) {
      float4 w0 = *(const float4*)&sW[k * 64 + co * 8];
      float4 w1 = *(const float4*)&sW[k * 64 + co * 8 + 4];
      const float* sb = &sIn[(w * 64 + no * 8) * 33 + k];
#pragma unroll
      for (int j = 0; j < 8; j++) {
        float xv = sb[j * 33];
        acc[j][0] += xv * w0.x; acc[j][1] += xv * w0.y;
        acc[j][2] += xv * w0.z; acc[j][3] += xv * w0.w;
        acc[j][4] += xv * w1.x; acc[j][5] += xv * w1.y;
        acc[j][6] += xv * w1.z; acc[j][7] += xv * w1.w;
      }
    }
    __syncthreads();
  }

  // attention scalars: reduce over the 8 co-lanes (low 3 bits of lane)
  float4 av0 = *(const float4*)&a_src[co * 8];
  float4 av1 = *(const float4*)&a_src[co * 8 + 4];
  float4 dv0 = *(const float4*)&a_dst[co * 8];
  float4 dv1 = *(const float4*)&a_dst[co * 8 + 4];
  float psk = 0.f, pdk = 0.f;
#pragma unroll
  for (int j = 0; j < 8; j++) {
    float ps = acc[j][0] * av0.x + acc[j][1] * av0.y + acc[j][2] * av0.z + acc[j][3] * av0.w
             + acc[j][4] * av1.x + acc[j][5] * av1.y + acc[j][6] * av1.z + acc[j][7] * av1.w;
    float pd = acc[j][0] * dv0.x + acc[j][1] * dv0.y + acc[j][2] * dv0.z + acc[j][3] * dv0.w
             + acc[j][4] * dv1.x + acc[j][5] * dv1.y + acc[j][6] * dv1.z + acc[j][7] * dv1.w;
    ps += __shfl_xor(ps, 1); ps += __shfl_xor(ps, 2); ps += __shfl_xor(ps, 4);
    pd += __shfl_xor(pd, 1); pd += __shfl_xor(pd, 2); pd += __shfl_xor(pd, 4);
    if (co == j) { psk = ps; pdk = pd; }
  }
  int nodeS = blockBase + w * 64 + no * 8 + co;
  if (nodeS < N) { as_[nodeS] = psk; ad_[nodeS] = pdk; }

  // h2 store: lane writes its 8 channels (16B) for each of its 8 nodes
#pragma unroll
  for (int j = 0; j < 8; j++) {
    int node = blockBase + w * 64 + no * 8 + j;
    if (node < N) {
      __half2 q[4];
      q[0] = __floats2half2_rn(acc[j][0], acc[j][1]);
      q[1] = __floats2half2_rn(acc[j][2], acc[j][3]);
      q[2] = __floats2half2_rn(acc[j][4], acc[j][5]);
      q[3] = __floats2half2_rn(acc[j][6], acc[j][7]);
      *(float4*)&h2[(size_t)node * 32 + co * 4] = *(float4*)q;
    }
  }
}

// ---------------- edge scores (edge-parallel, coalesced) ----------------
__global__ __launch_bounds__(256) void score_kernel(
    const float* __restrict__ as_, const float* __restrict__ ad_,
    const int* __restrict__ csr_src, const unsigned char* __restrict__ dst8,
    const int* __restrict__ row_start, float* __restrict__ coef, int N) {
  int b = blockIdx.x;
  int part = blockIdx.y;
  int nbase = b * 256;
  int nend = nbase + 256; if (nend > N) nend = N;
  int sBeg = row_start[nbase];
  int sEnd = row_start[nend];
  for (int s = sBeg + part * 256 + threadIdx.x; s < sEnd; s += 1024) {
    int src = csr_src[s];
    float e = as_[src] + ad_[nbase + dst8[s]];
    e = (e > 0.f) ? e : 0.2f * e;
    coef[s] = __expf(e);
  }
}

// ---------------- aggregation: out[n] = relu(sum coef*h[src]/den + b) -------
__global__ __launch_bounds__(256) void agg_kernel(
    const __half2* __restrict__ h2, const float* __restrict__ coef,
    const int* __restrict__ csr_src, const int* __restrict__ row_start,
    const float* __restrict__ b, float* __restrict__ out, int N) {
  int t = threadIdx.x;
  int lane = t & 63, w = t >> 6;
  int ng = lane >> 3, co = lane & 7;
  int n = blockIdx.x * 32 + w * 8 + ng;
  if (n >= N) return;
  int rs = row_start[n], re = row_start[n + 1];
  const float4* h4 = (const float4*)h2;  // 8 float4 (=128B) per node row

  float4 A0 = make_float4(0.f, 0.f, 0.f, 0.f);
  float4 A1 = make_float4(0.f, 0.f, 0.f, 0.f);
  float den = 0.f;
  for (int s = rs; s < re; s += 4) {
    float cf[4];
    int src[4];
#pragma unroll
    for (int j = 0; j < 4; j++) {
      int sj = s + j;
      int sc = (sj < re) ? sj : (re - 1);
      cf[j] = coef[sc];
      if (sj >= re) cf[j] = 0.f;
      src[j] = csr_src[sc];
    }
#pragma unroll
    for (int j = 0; j < 4; j++) {
      float4 hv = h4[(size_t)src[j] * 8 + co];
      const __half2* hp = (const __half2*)&hv;
      float2 f0 = __half22float2(hp[0]);
      float2 f1 = __half22float2(hp[1]);
      float2 f2 = __half22float2(hp[2]);
      float2 f3 = __half22float2(hp[3]);
      float c = cf[j];
      den += c;
      A0.x += c * f0.x; A0.y += c * f0.y; A0.z += c * f1.x; A0.w += c * f1.y;
      A1.x += c * f2.x; A1.y += c * f2.y; A1.z += c * f3.x; A1.w += c * f3.y;
    }
  }
  float inv = 1.0f / (den + 1e-16f);
  float4 b0 = *(const float4*)&b[co * 8];
  float4 b1 = *(const float4*)&b[co * 8 + 4];
  float4 o0, o1;
  o0.x = fmaxf(A0.x * inv + b0.x, 0.f);
  o0.y = fmaxf(A0.y * inv + b0.y, 0.f);
  o0.z = fmaxf(A0.z * inv + b0.z, 0.f);
  o0.w = fmaxf(A0.w * inv + b0.w, 0.f);
  o1.x = fmaxf(A1.x * inv + b1.x, 0.f);
  o1.y = fmaxf(A1.y * inv + b1.y, 0.f);
  o1.z = fmaxf(A1.z * inv + b1.z, 0.f);
  o1.w = fmaxf(A1.w * inv + b1.w, 0.f);
  *(float4*)&out[(size_t)n * 64 + co * 8] = o0;
  *(float4*)&out[(size_t)n * 64 + co * 8 + 4] = o1;
}

// ---------------- global max pool + root detection ----------------
__global__ void pool_kernel(const float* __restrict__ h, const int* __restrict__ batch,
                            float* __restrict__ pool, int* __restrict__ root,
                            int N, int chunk) {
  int t = threadIdx.x;
  int lane = t & 63, w = t >> 6;
  int row = blockIdx.x * 4 + w;
  int start = row * chunk;
  if (start >= N) return;
  int end = start + chunk; if (end > N) end = N;
  int cur_g = batch[start];
  if (lane == 0 && (start == 0 || batch[start - 1] != cur_g)) atomicMin(&root[cur_g], start);
  float rm = 0.0f;  // h >= 0 (post-relu), pool init 0
  for (int n = start; n < end; n++) {
    int g = batch[n];
    if (g != cur_g) {
      atomicMax((int*)&pool[(size_t)cur_g * 64 + lane], __float_as_int(rm));
      if (lane == 0) atomicMin(&root[g], n);
      cur_g = g;
      rm = 0.0f;
    }
    rm = fmaxf(rm, h[(size_t)n * 64 + lane]);
  }
  atomicMax((int*)&pool[(size_t)cur_g * 64 + lane], __float_as_int(rm));
}

// ---------------- final fused MLP head (wave per graph) ----------------
__global__ void final_kernel(const float* __restrict__ pool, const int* __restrict__ root,
                             const float* __restrict__ x,
                             const float* __restrict__ lin0_W, const float* __restrict__ lin0_b,
                             const float* __restrict__ linnews_W, const float* __restrict__ linnews_b,
                             const float* __restrict__ lin1_W, const float* __restrict__ lin1_b,
                             float* __restrict__ out, int G, int N) {
  int t = threadIdx.x;
  int lane = t & 63, w = t >> 6;
  int g = blockIdx.x * 4 + w;
  if (g >= G) return;
  float hp = 0.f;
  for (int k = 0; k < 64; k++) hp += pool[(size_t)g * 64 + k] * lin0_W[k * 64 + lane];
  hp = fmaxf(hp + lin0_b[lane], 0.f);
  int r = root[g]; if (r > N - 1) r = N - 1; if (r < 0) r = 0;
  float nw = 0.f;
  for (int k = 0; k < 128; k++) nw += x[(size_t)r * 128 + k] * linnews_W[k * 64 + lane];
  nw = fmaxf(nw + linnews_b[lane], 0.f);
  float p = hp * lin1_W[lane] + nw * lin1_W[64 + lane];
  for (int k = 1; k < 64; k <<= 1) p += __shfl_xor(p, k);
  if (lane == 0) out[g] = 1.0f / (1.0f + __expf(-(p + lin1_b[0])));
}

// ---------------- launch ----------------
extern "C" void kernel_launch(void* const* d_in, const int* in_sizes, int n_in,
                              void* d_out, int out_size, void* d_ws, size_t ws_size,
                              hipStream_t stream) {
  (void)n_in; (void)ws_size;
  const float* x      = (const float*)d_in[0];
  const int*   adj    = (const int*)d_in[1];
  const int*   batch  = (const int*)d_in[2];
  const float* W1     = (const float*)d_in[3];
  const float* asrc1  = (const float*)d_in[4];
  const float* adst1  = (const float*)d_in[5];
  const float* b1     = (const float*)d_in[6];
  const float* W2     = (const float*)d_in[7];
  const float* asrc2  = (const float*)d_in[8];
  const float* adst2  = (const float*)d_in[9];
  const float* b2     = (const float*)d_in[10];
  const float* W3     = (const float*)d_in[11];
  const float* asrc3  = (const float*)d_in[12];
  const float* adst3  = (const float*)d_in[13];
  const float* b3     = (const float*)d_in[14];
  const float* lnW    = (const float*)d_in[15];
  const float* lnb    = (const float*)d_in[16];
  const float* l0W    = (const float*)d_in[17];
  const float* l0b    = (const float*)d_in[18];
  const float* l1W    = (const float*)d_in[19];
  const float* l1b    = (const float*)d_in[20];
  float* outp = (float*)d_out;

  const int N = in_sizes[2];
  const int E = in_sizes[1] / 2;
  const int Etot = E + N;
  const int G = out_size;
  const int B = (N + 255) / 256;  // real buckets (<= BPAD)

  const int* src_e = adj;
  const int* dst_e = adj + E;

  uintptr_t p = (uintptr_t)d_ws;
  auto alloc = [&](size_t bytes) -> void* {
    void* r = (void*)p;
    p += (bytes + 255) & ~(size_t)255;
    return r;
  };
  int*     hist      = (int*)alloc((size_t)BPAD * NBLK * 4);
  int*     row_start = (int*)alloc((size_t)(N + 1) * 4);
  int*     csr_src   = (int*)alloc((size_t)Etot * 4);
  unsigned char* dst8 = (unsigned char*)alloc((size_t)Etot);
  float*   coef      = (float*)alloc((size_t)Etot * 4);
  unsigned int* ebuf = (unsigned int*)alloc((size_t)E * 4);
  __half2* h2        = (__half2*)alloc((size_t)N * 32 * 4);
  float*   bufA      = (float*)alloc((size_t)N * 64 * 4);
  float*   as_       = (float*)alloc((size_t)N * 4);
  float*   ad_       = (float*)alloc((size_t)N * 4);
  float*   pool      = (float*)alloc((size_t)G * 64 * 4);
  int*     root      = (int*)alloc((size_t)G * 4);

  init_kernel<<<dim3((G * 64 + THREADS - 1) / THREADS), dim3(THREADS), 0, stream>>>(pool, root, G);

  int chunk = (E + NBLK - 1) / NBLK;
  hist_kernel<<<dim3(NBLK), dim3(256), 0, stream>>>(dst_e, hist, E, chunk);
  hscan_kernel<<<dim3(1), dim3(256), 0, stream>>>(hist);
  scatter_kernel<<<dim3(NBLK), dim3(256), 0, stream>>>(src_e, dst_e, hist, ebuf, E, chunk);
  build_kernel<<<dim3(B), dim3(256), 0, stream>>>(ebuf, hist, row_start, csr_src, dst8, N, E);

  const int linGrid = (N + 255) / 256;
  const int aggGrid = (N + 31) / 32;
  dim3 scoreGrid(B, 4);

  // layer 1
  lin_attn_kernel<128><<<dim3(linGrid), dim3(256), 0, stream>>>(x, W1, asrc1, adst1, h2, as_, ad_, N);
  score_kernel<<<scoreGrid, dim3(256), 0, stream>>>(as_, ad_, csr_src, dst8, row_start, coef, N);
  agg_kernel<<<dim3(aggGrid), dim3(256), 0, stream>>>(h2, coef, csr_src, row_start, b1, bufA, N);
  // layer 2
  lin_attn_kernel<64><<<dim3(linGrid), dim3(256), 0, stream>>>(bufA, W2, asrc2, adst2, h2, as_, ad_, N);
  score_kernel<<<scoreGrid, dim3(256), 0, stream>>>(as_, ad_, csr_src, dst8, row_start, coef, N);
  agg_kernel<<<dim3(aggGrid), dim3(256), 0, stream>>>(h2, coef, csr_src, row_start, b2, bufA, N);
  // layer 3
  lin_attn_kernel<64><<<dim3(linGrid), dim3(256), 0, stream>>>(bufA, W3, asrc3, adst3, h2, as_, ad_, N);
  score_kernel<<<scoreGrid, dim3(256), 0, stream>>>(as_, ad_, csr_src, dst8, row_start, coef, N);
  agg_kernel<<<dim3(aggGrid), dim3(256), 0, stream>>>(h2, coef, csr_src, row_start, b3, bufA, N);

  // pool + root
  const int ROWS = 2048;
  int pchunk = (N + ROWS - 1) / ROWS;
  pool_kernel<<<dim3(ROWS / 4), dim3(256), 0, stream>>>(bufA, batch, pool, root, N, pchunk);

  // head
  final_kernel<<<dim3((G + 3) / 4), dim3(256), 0, stream>>>(
      pool, root, x, l0W, l0b, lnW, lnb, l1W, l1b, outp, G, N);
}

// Round 8
// 358.347 us; speedup vs baseline: 1.1310x; 1.1310x over previous
//
#include <hip/hip_runtime.h>
#include <hip/hip_fp16.h>
#include <cstdint>

#define THREADS 256
#define NBLK 64     // blocks for hist/scatter
#define BPAD 512    // padded bucket count (dst>>8; N<=131072)
#define LINBLK 640  // blocks for lin_attn (2560 waves; ~2.4 tiles/wave)

typedef _Float16 half8 __attribute__((ext_vector_type(8)));
typedef float v4f __attribute__((ext_vector_type(4)));

// ---------------- init ----------------
__global__ void init_kernel(float* pool, int* root, int G) {
  int i = blockIdx.x * blockDim.x + threadIdx.x;
  if (i < G * 64) pool[i] = 0.0f;
  if (i < G) root[i] = 0x7fffffff;
}

// ---------------- CSR build: bucket sort, no global atomics ----------------
__global__ __launch_bounds__(256) void hist_kernel(const int* __restrict__ dst_e,
                                                   int* __restrict__ hist, int E, int chunk) {
  __shared__ int hcnt[BPAD];
  int t = threadIdx.x, blk = blockIdx.x;
  for (int i = t; i < BPAD; i += 256) hcnt[i] = 0;
  __syncthreads();
  int s = blk * chunk, e = s + chunk;
  if (e > E) e = E;
  for (int i = s + t; i < e; i += 256) atomicAdd(&hcnt[dst_e[i] >> 8], 1);
  __syncthreads();
  for (int b = t; b < BPAD; b += 256) hist[b * NBLK + blk] = hcnt[b];
}

__global__ __launch_bounds__(256) void hscan_kernel(int* __restrict__ hist) {
  __shared__ int part[256];
  const int PER = (BPAD * NBLK) / 256;  // 128
  int t = threadIdx.x;
  int base = t * PER;
  int sum = 0;
  for (int k = 0; k < PER; k++) sum += hist[base + k];
  part[t] = sum;
  __syncthreads();
  int own = sum;
  for (int off = 1; off < 256; off <<= 1) {
    int v = (t >= off) ? part[t - off] : 0;
    __syncthreads();
    part[t] += v;
    __syncthreads();
  }
  int run = part[t] - own;
  for (int k = 0; k < PER; k++) {
    int h = hist[base + k];
    hist[base + k] = run;
    run += h;
  }
}

// scatter edges into bucket-partitioned ebuf, packed (src<<8)|(dst&255).
__global__ __launch_bounds__(256) void scatter_kernel(const int* __restrict__ src_e,
                                                      const int* __restrict__ dst_e,
                                                      const int* __restrict__ hist,
                                                      unsigned int* __restrict__ ebuf,
                                                      int E, int chunk) {
  __shared__ int cur[BPAD];
  int t = threadIdx.x, blk = blockIdx.x;
  for (int b = t; b < BPAD; b += 256) cur[b] = hist[b * NBLK + blk];
  __syncthreads();
  int s = blk * chunk, e = s + chunk;
  if (e > E) e = E;
  for (int i = s + t; i < e; i += 256) {
    int d = dst_e[i];
    unsigned int sv = (unsigned int)src_e[i];
    int slot = atomicAdd(&cur[d >> 8], 1);
    ebuf[slot] = (sv << 8) | (unsigned int)(d & 255);
  }
}

// per-bucket CSR finalize: row_start + csr_src + local-dst byte.
__global__ __launch_bounds__(256) void build_kernel(const unsigned int* __restrict__ ebuf,
                                                    const int* __restrict__ hist,
                                                    int* __restrict__ row_start,
                                                    int* __restrict__ csr_src,
                                                    unsigned char* __restrict__ dst8,
                                                    int N, int E) {
  __shared__ int counts[256];
  __shared__ int sc[256];
  __shared__ int curw[256];
  int t = threadIdx.x, b = blockIdx.x;
  int nbase = b * 256;
  int ebase = hist[b * NBLK];
  int eend = hist[(b + 1) * NBLK];
  counts[t] = 0;
  __syncthreads();
  int ecount = eend - ebase;
  for (int i = t; i < ecount; i += 256)
    atomicAdd(&counts[ebuf[ebase + i] & 255u], 1);
  __syncthreads();
  int n = nbase + t;
  int val = (n < N) ? counts[t] + 1 : 0;  // +1 self-loop
  sc[t] = val;
  __syncthreads();
  int own = val;
  for (int off = 1; off < 256; off <<= 1) {
    int v = (t >= off) ? sc[t - off] : 0;
    __syncthreads();
    sc[t] += v;
    __syncthreads();
  }
  int myloc = sc[t] - own;  // exclusive
  int rowb = ebase + nbase;  // prior real edges + prior self-loops
  if (n < N) {
    row_start[n] = rowb + myloc;
    csr_src[rowb + myloc + counts[t]] = n;  // self-loop in last slot
    dst8[rowb + myloc + counts[t]] = (unsigned char)t;
    if (n == N - 1) row_start[N] = rowb + myloc + counts[t] + 1;
  }
  curw[t] = rowb + myloc;
  __syncthreads();
  for (int i = t; i < ecount; i += 256) {
    unsigned int ev = ebuf[ebase + i];
    int ld = (int)(ev & 255u);
    int pos = atomicAdd(&curw[ld], 1);
    csr_src[pos] = (int)(ev >> 8);
    dst8[pos] = (unsigned char)ld;
  }
}

// ---------------- linear + attention scalars (MFMA) ----------------
// h = in @ W via v_mfma_f32_16x16x32_f16. One 16-node tile per wave per
// iteration. B-frags (whole W, 4 n-tiles x NKC k-chunks) live in registers
// across the grid-stride tile loop. Layouts (m89/m91/m120 verified):
//   A[m=lane&15][k=quad*8+j]; B[k=quad*8+j][n=lane&15];
//   D: row(m)=quad*4+reg, col(n)=lane&15.
template <int K>
__global__ __launch_bounds__(256) void lin_attn_kernel(
    const float* __restrict__ in, const float* __restrict__ W,
    const float* __restrict__ a_src, const float* __restrict__ a_dst,
    __half2* __restrict__ h2, float* __restrict__ as_, float* __restrict__ ad_,
    int N, int nwaves) {
  constexpr int NKC = K / 32;
  __shared__ _Float16 sh[4][16 * 64];  // per-wave transpose buffer (8 KB)
  const int t = threadIdx.x;
  const int lane = t & 63, w = t >> 6;
  const int col = lane & 15, quad = lane >> 4;
  const int wid = blockIdx.x * 4 + w;

  // B fragments from W (fp32 -> fp16), reused across all tiles
  half8 bf[4][NKC];
#pragma unroll
  for (int nt = 0; nt < 4; nt++)
#pragma unroll
    for (int kc = 0; kc < NKC; kc++) {
      half8 v;
#pragma unroll
      for (int j = 0; j < 8; j++)
        v[j] = (_Float16)W[(kc * 32 + quad * 8 + j) * 64 + nt * 16 + col];
      bf[nt][kc] = v;
    }
  float sa[4], sd[4];
#pragma unroll
  for (int nt = 0; nt < 4; nt++) {
    sa[nt] = a_src[nt * 16 + col];
    sd[nt] = a_dst[nt * 16 + col];
  }

  const int ntiles = (N + 15) >> 4;
  for (int tile = wid; tile < ntiles; tile += nwaves) {
    const int nb = tile << 4;
    int nodeA = nb + col;
    if (nodeA >= N) nodeA = N - 1;
    const float* arow = in + (size_t)nodeA * K + quad * 8;

    v4f acc[4];
#pragma unroll
    for (int nt = 0; nt < 4; nt++) acc[nt] = (v4f){0.f, 0.f, 0.f, 0.f};

#pragma unroll
    for (int kc = 0; kc < NKC; kc++) {
      float4 f0 = *(const float4*)(arow + kc * 32);
      float4 f1 = *(const float4*)(arow + kc * 32 + 4);
      half8 a;
      a[0] = (_Float16)f0.x; a[1] = (_Float16)f0.y;
      a[2] = (_Float16)f0.z; a[3] = (_Float16)f0.w;
      a[4] = (_Float16)f1.x; a[5] = (_Float16)f1.y;
      a[6] = (_Float16)f1.z; a[7] = (_Float16)f1.w;
#pragma unroll
      for (int nt = 0; nt < 4; nt++)
        acc[nt] = __builtin_amdgcn_mfma_f32_16x16x32_f16(a, bf[nt][kc], acc[nt], 0, 0, 0);
    }

    // attention scalars: lane's 4 nodes (regs) x 4 channels (nt); reduce over col group
    float ps[4], pd[4];
#pragma unroll
    for (int r = 0; r < 4; r++) { ps[r] = 0.f; pd[r] = 0.f; }
#pragma unroll
    for (int nt = 0; nt < 4; nt++)
#pragma unroll
      for (int r = 0; r < 4; r++) {
        ps[r] += acc[nt][r] * sa[nt];
        pd[r] += acc[nt][r] * sd[nt];
      }
#pragma unroll
    for (int r = 0; r < 4; r++)
#pragma unroll
      for (int m = 1; m < 16; m <<= 1) {
        ps[r] += __shfl_xor(ps[r], m);
        pd[r] += __shfl_xor(pd[r], m);
      }
    if (col == 0) {
#pragma unroll
      for (int r = 0; r < 4; r++) {
        int node = nb + quad * 4 + r;
        if (node < N) { as_[node] = ps[r]; ad_[node] = pd[r]; }
      }
    }

    // h2 store via wave-private LDS transpose (no barrier: same wave r/w)
#pragma unroll
    for (int nt = 0; nt < 4; nt++)
#pragma unroll
      for (int r = 0; r < 4; r++)
        sh[w][(quad * 4 + r) * 64 + nt * 16 + col] = (_Float16)acc[nt][r];
    int nr = lane >> 2, c4 = lane & 3;
    float4 v0 = *(float4*)&sh[w][nr * 64 + c4 * 16];
    float4 v1 = *(float4*)&sh[w][nr * 64 + c4 * 16 + 8];
    int node = nb + nr;
    if (node < N) {
      *(float4*)&h2[(size_t)node * 32 + c4 * 8] = v0;
      *(float4*)&h2[(size_t)node * 32 + c4 * 8 + 4] = v1;
    }
  }
}

// ---------------- edge scores (edge-parallel, coalesced) ----------------
__global__ __launch_bounds__(256) void score_kernel(
    const float* __restrict__ as_, const float* __restrict__ ad_,
    const int* __restrict__ csr_src, const unsigned char* __restrict__ dst8,
    const int* __restrict__ row_start, float* __restrict__ coef, int N) {
  int b = blockIdx.x;
  int part = blockIdx.y;
  int nbase = b * 256;
  int nend = nbase + 256; if (nend > N) nend = N;
  int sBeg = row_start[nbase];
  int sEnd = row_start[nend];
  for (int s = sBeg + part * 256 + threadIdx.x; s < sEnd; s += 1024) {
    int src = csr_src[s];
    float e = as_[src] + ad_[nbase + dst8[s]];
    e = (e > 0.f) ? e : 0.2f * e;
    coef[s] = __expf(e);
  }
}

// ---------------- aggregation: out[n] = relu(sum coef*h[src]/den + b) -------
__global__ __launch_bounds__(256) void agg_kernel(
    const __half2* __restrict__ h2, const float* __restrict__ coef,
    const int* __restrict__ csr_src, const int* __restrict__ row_start,
    const float* __restrict__ b, float* __restrict__ out, int N) {
  int t = threadIdx.x;
  int lane = t & 63, w = t >> 6;
  int ng = lane >> 3, co = lane & 7;
  int n = blockIdx.x * 32 + w * 8 + ng;
  if (n >= N) return;
  int rs = row_start[n], re = row_start[n + 1];
  const float4* h4 = (const float4*)h2;  // 8 float4 (=128B) per node row

  float4 A0 = make_float4(0.f, 0.f, 0.f, 0.f);
  float4 A1 = make_float4(0.f, 0.f, 0.f, 0.f);
  float den = 0.f;
  for (int s = rs; s < re; s += 4) {
    float cf[4];
    int src[4];
#pragma unroll
    for (int j = 0; j < 4; j++) {
      int sj = s + j;
      int sc = (sj < re) ? sj : (re - 1);
      cf[j] = coef[sc];
      if (sj >= re) cf[j] = 0.f;
      src[j] = csr_src[sc];
    }
#pragma unroll
    for (int j = 0; j < 4; j++) {
      float4 hv = h4[(size_t)src[j] * 8 + co];
      const __half2* hp = (const __half2*)&hv;
      float2 f0 = __half22float2(hp[0]);
      float2 f1 = __half22float2(hp[1]);
      float2 f2 = __half22float2(hp[2]);
      float2 f3 = __half22float2(hp[3]);
      float c = cf[j];
      den += c;
      A0.x += c * f0.x; A0.y += c * f0.y; A0.z += c * f1.x; A0.w += c * f1.y;
      A1.x += c * f2.x; A1.y += c * f2.y; A1.z += c * f3.x; A1.w += c * f3.y;
    }
  }
  float inv = 1.0f / (den + 1e-16f);
  float4 b0 = *(const float4*)&b[co * 8];
  float4 b1 = *(const float4*)&b[co * 8 + 4];
  float4 o0, o1;
  o0.x = fmaxf(A0.x * inv + b0.x, 0.f);
  o0.y = fmaxf(A0.y * inv + b0.y, 0.f);
  o0.z = fmaxf(A0.z * inv + b0.z, 0.f);
  o0.w = fmaxf(A0.w * inv + b0.w, 0.f);
  o1.x = fmaxf(A1.x * inv + b1.x, 0.f);
  o1.y = fmaxf(A1.y * inv + b1.y, 0.f);
  o1.z = fmaxf(A1.z * inv + b1.z, 0.f);
  o1.w = fmaxf(A1.w * inv + b1.w, 0.f);
  *(float4*)&out[(size_t)n * 64 + co * 8] = o0;
  *(float4*)&out[(size_t)n * 64 + co * 8 + 4] = o1;
}

// ---------------- global max pool + root detection ----------------
__global__ void pool_kernel(const float* __restrict__ h, const int* __restrict__ batch,
                            float* __restrict__ pool, int* __restrict__ root,
                            int N, int chunk) {
  int t = threadIdx.x;
  int lane = t & 63, w = t >> 6;
  int row = blockIdx.x * 4 + w;
  int start = row * chunk;
  if (start >= N) return;
  int end = start + chunk; if (end > N) end = N;
  int cur_g = batch[start];
  if (lane == 0 && (start == 0 || batch[start - 1] != cur_g)) atomicMin(&root[cur_g], start);
  float rm = 0.0f;  // h >= 0 (post-relu), pool init 0
  for (int n = start; n < end; n++) {
    int g = batch[n];
    if (g != cur_g) {
      atomicMax((int*)&pool[(size_t)cur_g * 64 + lane], __float_as_int(rm));
      if (lane == 0) atomicMin(&root[g], n);
      cur_g = g;
      rm = 0.0f;
    }
    rm = fmaxf(rm, h[(size_t)n * 64 + lane]);
  }
  atomicMax((int*)&pool[(size_t)cur_g * 64 + lane], __float_as_int(rm));
}

// ---------------- final fused MLP head (wave per graph) ----------------
__global__ void final_kernel(const float* __restrict__ pool, const int* __restrict__ root,
                             const float* __restrict__ x,
                             const float* __restrict__ lin0_W, const float* __restrict__ lin0_b,
                             const float* __restrict__ linnews_W, const float* __restrict__ linnews_b,
                             const float* __restrict__ lin1_W, const float* __restrict__ lin1_b,
                             float* __restrict__ out, int G, int N) {
  int t = threadIdx.x;
  int lane = t & 63, w = t >> 6;
  int g = blockIdx.x * 4 + w;
  if (g >= G) return;
  float hp = 0.f;
  for (int k = 0; k < 64; k++) hp += pool[(size_t)g * 64 + k] * lin0_W[k * 64 + lane];
  hp = fmaxf(hp + lin0_b[lane], 0.f);
  int r = root[g]; if (r > N - 1) r = N - 1; if (r < 0) r = 0;
  float nw = 0.f;
  for (int k = 0; k < 128; k++) nw += x[(size_t)r * 128 + k] * linnews_W[k * 64 + lane];
  nw = fmaxf(nw + linnews_b[lane], 0.f);
  float p = hp * lin1_W[lane] + nw * lin1_W[64 + lane];
  for (int k = 1; k < 64; k <<= 1) p += __shfl_xor(p, k);
  if (lane == 0) out[g] = 1.0f / (1.0f + __expf(-(p + lin1_b[0])));
}

// ---------------- launch ----------------
extern "C" void kernel_launch(void* const* d_in, const int* in_sizes, int n_in,
                              void* d_out, int out_size, void* d_ws, size_t ws_size,
                              hipStream_t stream) {
  (void)n_in; (void)ws_size;
  const float* x      = (const float*)d_in[0];
  const int*   adj    = (const int*)d_in[1];
  const int*   batch  = (const int*)d_in[2];
  const float* W1     = (const float*)d_in[3];
  const float* asrc1  = (const float*)d_in[4];
  const float* adst1  = (const float*)d_in[5];
  const float* b1     = (const float*)d_in[6];
  const float* W2     = (const float*)d_in[7];
  const float* asrc2  = (const float*)d_in[8];
  const float* adst2  = (const float*)d_in[9];
  const float* b2     = (const float*)d_in[10];
  const float* W3     = (const float*)d_in[11];
  const float* asrc3  = (const float*)d_in[12];
  const float* adst3  = (const float*)d_in[13];
  const float* b3     = (const float*)d_in[14];
  const float* lnW    = (const float*)d_in[15];
  const float* lnb    = (const float*)d_in[16];
  const float* l0W    = (const float*)d_in[17];
  const float* l0b    = (const float*)d_in[18];
  const float* l1W    = (const float*)d_in[19];
  const float* l1b    = (const float*)d_in[20];
  float* outp = (float*)d_out;

  const int N = in_sizes[2];
  const int E = in_sizes[1] / 2;
  const int Etot = E + N;
  const int G = out_size;
  const int B = (N + 255) / 256;  // real buckets (<= BPAD)

  const int* src_e = adj;
  const int* dst_e = adj + E;

  uintptr_t p = (uintptr_t)d_ws;
  auto alloc = [&](size_t bytes) -> void* {
    void* r = (void*)p;
    p += (bytes + 255) & ~(size_t)255;
    return r;
  };
  int*     hist      = (int*)alloc((size_t)BPAD * NBLK * 4);
  int*     row_start = (int*)alloc((size_t)(N + 1) * 4);
  int*     csr_src   = (int*)alloc((size_t)Etot * 4);
  unsigned char* dst8 = (unsigned char*)alloc((size_t)Etot);
  float*   coef      = (float*)alloc((size_t)Etot * 4);
  unsigned int* ebuf = (unsigned int*)alloc((size_t)E * 4);
  __half2* h2        = (__half2*)alloc((size_t)N * 32 * 4);
  float*   bufA      = (float*)alloc((size_t)N * 64 * 4);
  float*   as_       = (float*)alloc((size_t)N * 4);
  float*   ad_       = (float*)alloc((size_t)N * 4);
  float*   pool      = (float*)alloc((size_t)G * 64 * 4);
  int*     root      = (int*)alloc((size_t)G * 4);

  init_kernel<<<dim3((G * 64 + THREADS - 1) / THREADS), dim3(THREADS), 0, stream>>>(pool, root, G);

  int chunk = (E + NBLK - 1) / NBLK;
  hist_kernel<<<dim3(NBLK), dim3(256), 0, stream>>>(dst_e, hist, E, chunk);
  hscan_kernel<<<dim3(1), dim3(256), 0, stream>>>(hist);
  scatter_kernel<<<dim3(NBLK), dim3(256), 0, stream>>>(src_e, dst_e, hist, ebuf, E, chunk);
  build_kernel<<<dim3(B), dim3(256), 0, stream>>>(ebuf, hist, row_start, csr_src, dst8, N, E);

  const int aggGrid = (N + 31) / 32;
  const int nwaves = LINBLK * 4;
  dim3 scoreGrid(B, 4);

  // layer 1
  lin_attn_kernel<128><<<dim3(LINBLK), dim3(256), 0, stream>>>(x, W1, asrc1, adst1, h2, as_, ad_, N, nwaves);
  score_kernel<<<scoreGrid, dim3(256), 0, stream>>>(as_, ad_, csr_src, dst8, row_start, coef, N);
  agg_kernel<<<dim3(aggGrid), dim3(256), 0, stream>>>(h2, coef, csr_src, row_start, b1, bufA, N);
  // layer 2
  lin_attn_kernel<64><<<dim3(LINBLK), dim3(256), 0, stream>>>(bufA, W2, asrc2, adst2, h2, as_, ad_, N, nwaves);
  score_kernel<<<scoreGrid, dim3(256), 0, stream>>>(as_, ad_, csr_src, dst8, row_start, coef, N);
  agg_kernel<<<dim3(aggGrid), dim3(256), 0, stream>>>(h2, coef, csr_src, row_start, b2, bufA, N);
  // layer 3
  lin_attn_kernel<64><<<dim3(LINBLK), dim3(256), 0, stream>>>(bufA, W3, asrc3, adst3, h2, as_, ad_, N, nwaves);
  score_kernel<<<scoreGrid, dim3(256), 0, stream>>>(as_, ad_, csr_src, dst8, row_start, coef, N);
  agg_kernel<<<dim3(aggGrid), dim3(256), 0, stream>>>(h2, coef, csr_src, row_start, b3, bufA, N);

  // pool + root
  const int ROWS = 2048;
  int pchunk = (N + ROWS - 1) / ROWS;
  pool_kernel<<<dim3(ROWS / 4), dim3(256), 0, stream>>>(bufA, batch, pool, root, N, pchunk);

  // head
  final_kernel<<<dim3((G + 3) / 4), dim3(256), 0, stream>>>(
      pool, root, x, l0W, l0b, lnW, lnb, l1W, l1b, outp, G, N);
}

// Round 9
// 317.628 us; speedup vs baseline: 1.2760x; 1.1282x over previous
//
#include <hip/hip_runtime.h>
#include <hip/hip_fp16.h>
#include <cstdint>
#include <type_traits>

#define THREADS 256
#define NBLK 64     // blocks for hist/scatter
#define BPAD 512    // padded bucket count (dst>>8; N<=131072)
#define LINBLK 640  // blocks for lin_attn

typedef _Float16 half8 __attribute__((ext_vector_type(8)));
typedef float v4f __attribute__((ext_vector_type(4)));

// ---------------- CSR build: bucket sort, no global atomics ----------------
// block 0 also zero-inits pool/root (used much later; no ordering hazard).
__global__ __launch_bounds__(256) void hist_kernel(const int* __restrict__ dst_e,
                                                   int* __restrict__ hist, int E, int chunk,
                                                   float* __restrict__ pool, int* __restrict__ root,
                                                   int G) {
  __shared__ int hcnt[BPAD];
  int t = threadIdx.x, blk = blockIdx.x;
  if (blk == 0) {
    for (int i = t; i < G * 64; i += 256) pool[i] = 0.0f;
    for (int i = t; i < G; i += 256) root[i] = 0x7fffffff;
  }
  for (int i = t; i < BPAD; i += 256) hcnt[i] = 0;
  __syncthreads();
  int s = blk * chunk, e = s + chunk;
  if (e > E) e = E;
  for (int i = s + t; i < e; i += 256) atomicAdd(&hcnt[dst_e[i] >> 8], 1);
  __syncthreads();
  for (int b = t; b < BPAD; b += 256) hist[b * NBLK + blk] = hcnt[b];
}

__global__ __launch_bounds__(256) void hscan_kernel(int* __restrict__ hist) {
  __shared__ int part[256];
  const int PER = (BPAD * NBLK) / 256;  // 128
  int t = threadIdx.x;
  int base = t * PER;
  int sum = 0;
  for (int k = 0; k < PER; k++) sum += hist[base + k];
  part[t] = sum;
  __syncthreads();
  int own = sum;
  for (int off = 1; off < 256; off <<= 1) {
    int v = (t >= off) ? part[t - off] : 0;
    __syncthreads();
    part[t] += v;
    __syncthreads();
  }
  int run = part[t] - own;
  for (int k = 0; k < PER; k++) {
    int h = hist[base + k];
    hist[base + k] = run;
    run += h;
  }
}

// scatter edges into bucket-partitioned ebuf, packed (src<<8)|(dst&255).
__global__ __launch_bounds__(256) void scatter_kernel(const int* __restrict__ src_e,
                                                      const int* __restrict__ dst_e,
                                                      const int* __restrict__ hist,
                                                      unsigned int* __restrict__ ebuf,
                                                      int E, int chunk) {
  __shared__ int cur[BPAD];
  int t = threadIdx.x, blk = blockIdx.x;
  for (int b = t; b < BPAD; b += 256) cur[b] = hist[b * NBLK + blk];
  __syncthreads();
  int s = blk * chunk, e = s + chunk;
  if (e > E) e = E;
  for (int i = s + t; i < e; i += 256) {
    int d = dst_e[i];
    unsigned int sv = (unsigned int)src_e[i];
    int slot = atomicAdd(&cur[d >> 8], 1);
    ebuf[slot] = (sv << 8) | (unsigned int)(d & 255);
  }
}

// per-bucket CSR finalize: row_start + csr_src (+self-loop in last slot).
__global__ __launch_bounds__(256) void build_kernel(const unsigned int* __restrict__ ebuf,
                                                    const int* __restrict__ hist,
                                                    int* __restrict__ row_start,
                                                    int* __restrict__ csr_src,
                                                    int N, int E) {
  __shared__ int counts[256];
  __shared__ int sc[256];
  __shared__ int curw[256];
  int t = threadIdx.x, b = blockIdx.x;
  int nbase = b * 256;
  int ebase = hist[b * NBLK];
  int eend = hist[(b + 1) * NBLK];
  counts[t] = 0;
  __syncthreads();
  int ecount = eend - ebase;
  for (int i = t; i < ecount; i += 256)
    atomicAdd(&counts[ebuf[ebase + i] & 255u], 1);
  __syncthreads();
  int n = nbase + t;
  int val = (n < N) ? counts[t] + 1 : 0;  // +1 self-loop
  sc[t] = val;
  __syncthreads();
  int own = val;
  for (int off = 1; off < 256; off <<= 1) {
    int v = (t >= off) ? sc[t - off] : 0;
    __syncthreads();
    sc[t] += v;
    __syncthreads();
  }
  int myloc = sc[t] - own;  // exclusive
  int rowb = ebase + nbase;  // prior real edges + prior self-loops
  if (n < N) {
    row_start[n] = rowb + myloc;
    csr_src[rowb + myloc + counts[t]] = n;  // self-loop in last slot
    if (n == N - 1) row_start[N] = rowb + myloc + counts[t] + 1;
  }
  curw[t] = rowb + myloc;
  __syncthreads();
  for (int i = t; i < ecount; i += 256) {
    unsigned int ev = ebuf[ebase + i];
    int pos = atomicAdd(&curw[ev & 255u], 1);
    csr_src[pos] = (int)(ev >> 8);
  }
}

// ---------------- linear + attention scalars (MFMA) ----------------
// h = in @ W via v_mfma_f32_16x16x32_f16. Input fp32 (layer 1) or fp16
// (layers 2-3, packed node-major 64 halves/row). Layouts (m89/m91/m120):
//   A[m=lane&15][k=quad*8+j]; B[k=quad*8+j][n=lane&15];
//   D: row(m)=quad*4+reg, col(n)=lane&15.
template <int K, typename TIN>
__global__ __launch_bounds__(256) void lin_attn_kernel(
    const TIN* __restrict__ in, const float* __restrict__ W,
    const float* __restrict__ a_src, const float* __restrict__ a_dst,
    __half2* __restrict__ h2, float* __restrict__ as_, float* __restrict__ ad_,
    int N, int nwaves) {
  constexpr int NKC = K / 32;
  __shared__ _Float16 sh[4][16 * 64];  // per-wave transpose buffer (8 KB)
  const int t = threadIdx.x;
  const int lane = t & 63, w = t >> 6;
  const int col = lane & 15, quad = lane >> 4;
  const int wid = blockIdx.x * 4 + w;

  // B fragments from W (fp32 -> fp16), reused across all tiles
  half8 bf[4][NKC];
#pragma unroll
  for (int nt = 0; nt < 4; nt++)
#pragma unroll
    for (int kc = 0; kc < NKC; kc++) {
      half8 v;
#pragma unroll
      for (int j = 0; j < 8; j++)
        v[j] = (_Float16)W[(kc * 32 + quad * 8 + j) * 64 + nt * 16 + col];
      bf[nt][kc] = v;
    }
  float sa[4], sd[4];
#pragma unroll
  for (int nt = 0; nt < 4; nt++) {
    sa[nt] = a_src[nt * 16 + col];
    sd[nt] = a_dst[nt * 16 + col];
  }

  const int ntiles = (N + 15) >> 4;
  for (int tile = wid; tile < ntiles; tile += nwaves) {
    const int nb = tile << 4;
    int nodeA = nb + col;
    if (nodeA >= N) nodeA = N - 1;
    const TIN* arow = in + (size_t)nodeA * K + quad * 8;

    v4f acc[4];
#pragma unroll
    for (int nt = 0; nt < 4; nt++) acc[nt] = (v4f){0.f, 0.f, 0.f, 0.f};

#pragma unroll
    for (int kc = 0; kc < NKC; kc++) {
      half8 a;
      if constexpr (std::is_same<TIN, float>::value) {
        float4 f0 = *(const float4*)(arow + kc * 32);
        float4 f1 = *(const float4*)(arow + kc * 32 + 4);
        a[0] = (_Float16)f0.x; a[1] = (_Float16)f0.y;
        a[2] = (_Float16)f0.z; a[3] = (_Float16)f0.w;
        a[4] = (_Float16)f1.x; a[5] = (_Float16)f1.y;
        a[6] = (_Float16)f1.z; a[7] = (_Float16)f1.w;
      } else {
        a = *(const half8*)(arow + kc * 32);
      }
#pragma unroll
      for (int nt = 0; nt < 4; nt++)
        acc[nt] = __builtin_amdgcn_mfma_f32_16x16x32_f16(a, bf[nt][kc], acc[nt], 0, 0, 0);
    }

    // attention scalars: reduce over the col group
    float ps[4], pd[4];
#pragma unroll
    for (int r = 0; r < 4; r++) { ps[r] = 0.f; pd[r] = 0.f; }
#pragma unroll
    for (int nt = 0; nt < 4; nt++)
#pragma unroll
      for (int r = 0; r < 4; r++) {
        ps[r] += acc[nt][r] * sa[nt];
        pd[r] += acc[nt][r] * sd[nt];
      }
#pragma unroll
    for (int r = 0; r < 4; r++)
#pragma unroll
      for (int m = 1; m < 16; m <<= 1) {
        ps[r] += __shfl_xor(ps[r], m);
        pd[r] += __shfl_xor(pd[r], m);
      }
    if (col == 0) {
#pragma unroll
      for (int r = 0; r < 4; r++) {
        int node = nb + quad * 4 + r;
        if (node < N) { as_[node] = ps[r]; ad_[node] = pd[r]; }
      }
    }

    // h2 store via wave-private LDS transpose (no barrier: same wave r/w)
#pragma unroll
    for (int nt = 0; nt < 4; nt++)
#pragma unroll
      for (int r = 0; r < 4; r++)
        sh[w][(quad * 4 + r) * 64 + nt * 16 + col] = (_Float16)acc[nt][r];
    int nr = lane >> 2, c4 = lane & 3;
    float4 v0 = *(float4*)&sh[w][nr * 64 + c4 * 16];
    float4 v1 = *(float4*)&sh[w][nr * 64 + c4 * 16 + 8];
    int node = nb + nr;
    if (node < N) {
      *(float4*)&h2[(size_t)node * 32 + c4 * 8] = v0;
      *(float4*)&h2[(size_t)node * 32 + c4 * 8 + 4] = v1;
    }
  }
}

// ---------------- fused score + aggregation ----------------
// out16[n] = relu( (sum_e exp(leaky(as_[src]+ad_[n])) * h[src]) / den + b )
// 8 lanes per node (8 nodes/wave); lane co owns 8 channels. as_/csr loads
// are 8-lane broadcast; exp computed redundantly per co-octet (1/8 wave-inst
// per edge). Output packed fp16 (node-major 64 halves) for the next layer.
__global__ __launch_bounds__(256) void agg_kernel(
    const __half2* __restrict__ h2, const float* __restrict__ as_, const float* __restrict__ ad_,
    const int* __restrict__ csr_src, const int* __restrict__ row_start,
    const float* __restrict__ b, _Float16* __restrict__ out16, int N) {
  int t = threadIdx.x;
  int lane = t & 63, w = t >> 6;
  int ng = lane >> 3, co = lane & 7;
  int n = blockIdx.x * 32 + w * 8 + ng;
  if (n >= N) return;
  int rs = row_start[n], re = row_start[n + 1];
  float adn = ad_[n];
  const float4* h4 = (const float4*)h2;  // 8 float4 (=128B) per node row

  float4 A0 = make_float4(0.f, 0.f, 0.f, 0.f);
  float4 A1 = make_float4(0.f, 0.f, 0.f, 0.f);
  float den = 0.f;
  for (int s = rs; s < re; s += 4) {
    int src[4];
#pragma unroll
    for (int j = 0; j < 4; j++) {
      int sj = s + j;
      src[j] = csr_src[(sj < re) ? sj : (re - 1)];
    }
    float cf[4];
#pragma unroll
    for (int j = 0; j < 4; j++) {
      float e = as_[src[j]] + adn;
      e = fmaxf(e, 0.2f * e);  // leaky_relu(0.2)
      cf[j] = (s + j < re) ? __expf(e) : 0.f;
    }
#pragma unroll
    for (int j = 0; j < 4; j++) {
      float4 hv = h4[(size_t)src[j] * 8 + co];
      const __half2* hp = (const __half2*)&hv;
      float2 f0 = __half22float2(hp[0]);
      float2 f1 = __half22float2(hp[1]);
      float2 f2 = __half22float2(hp[2]);
      float2 f3 = __half22float2(hp[3]);
      float c = cf[j];
      den += c;
      A0.x += c * f0.x; A0.y += c * f0.y; A0.z += c * f1.x; A0.w += c * f1.y;
      A1.x += c * f2.x; A1.y += c * f2.y; A1.z += c * f3.x; A1.w += c * f3.y;
    }
  }
  float inv = 1.0f / (den + 1e-16f);
  float4 b0 = *(const float4*)&b[co * 8];
  float4 b1 = *(const float4*)&b[co * 8 + 4];
  _Float16 o[8];
  o[0] = (_Float16)fmaxf(A0.x * inv + b0.x, 0.f);
  o[1] = (_Float16)fmaxf(A0.y * inv + b0.y, 0.f);
  o[2] = (_Float16)fmaxf(A0.z * inv + b0.z, 0.f);
  o[3] = (_Float16)fmaxf(A0.w * inv + b0.w, 0.f);
  o[4] = (_Float16)fmaxf(A1.x * inv + b1.x, 0.f);
  o[5] = (_Float16)fmaxf(A1.y * inv + b1.y, 0.f);
  o[6] = (_Float16)fmaxf(A1.z * inv + b1.z, 0.f);
  o[7] = (_Float16)fmaxf(A1.w * inv + b1.w, 0.f);
  *(float4*)&out16[(size_t)n * 64 + co * 8] = *(float4*)o;
}

// ---------------- global max pool + root detection (fp16 input) ----------
__global__ void pool_kernel(const _Float16* __restrict__ h, const int* __restrict__ batch,
                            float* __restrict__ pool, int* __restrict__ root,
                            int N, int chunk) {
  int t = threadIdx.x;
  int lane = t & 63, w = t >> 6;
  int row = blockIdx.x * 4 + w;
  int start = row * chunk;
  if (start >= N) return;
  int end = start + chunk; if (end > N) end = N;
  int cur_g = batch[start];
  if (lane == 0 && (start == 0 || batch[start - 1] != cur_g)) atomicMin(&root[cur_g], start);
  float rm = 0.0f;  // h >= 0 (post-relu), pool init 0
  for (int n = start; n < end; n++) {
    int g = batch[n];
    if (g != cur_g) {
      atomicMax((int*)&pool[(size_t)cur_g * 64 + lane], __float_as_int(rm));
      if (lane == 0) atomicMin(&root[g], n);
      cur_g = g;
      rm = 0.0f;
    }
    rm = fmaxf(rm, (float)h[(size_t)n * 64 + lane]);
  }
  atomicMax((int*)&pool[(size_t)cur_g * 64 + lane], __float_as_int(rm));
}

// ---------------- final fused MLP head (wave per graph) ----------------
__global__ void final_kernel(const float* __restrict__ pool, const int* __restrict__ root,
                             const float* __restrict__ x,
                             const float* __restrict__ lin0_W, const float* __restrict__ lin0_b,
                             const float* __restrict__ linnews_W, const float* __restrict__ linnews_b,
                             const float* __restrict__ lin1_W, const float* __restrict__ lin1_b,
                             float* __restrict__ out, int G, int N) {
  int t = threadIdx.x;
  int lane = t & 63, w = t >> 6;
  int g = blockIdx.x * 4 + w;
  if (g >= G) return;
  float hp = 0.f;
  for (int k = 0; k < 64; k++) hp += pool[(size_t)g * 64 + k] * lin0_W[k * 64 + lane];
  hp = fmaxf(hp + lin0_b[lane], 0.f);
  int r = root[g]; if (r > N - 1) r = N - 1; if (r < 0) r = 0;
  float nw = 0.f;
  for (int k = 0; k < 128; k++) nw += x[(size_t)r * 128 + k] * linnews_W[k * 64 + lane];
  nw = fmaxf(nw + linnews_b[lane], 0.f);
  float p = hp * lin1_W[lane] + nw * lin1_W[64 + lane];
  for (int k = 1; k < 64; k <<= 1) p += __shfl_xor(p, k);
  if (lane == 0) out[g] = 1.0f / (1.0f + __expf(-(p + lin1_b[0])));
}

// ---------------- launch ----------------
extern "C" void kernel_launch(void* const* d_in, const int* in_sizes, int n_in,
                              void* d_out, int out_size, void* d_ws, size_t ws_size,
                              hipStream_t stream) {
  (void)n_in; (void)ws_size;
  const float* x      = (const float*)d_in[0];
  const int*   adj    = (const int*)d_in[1];
  const int*   batch  = (const int*)d_in[2];
  const float* W1     = (const float*)d_in[3];
  const float* asrc1  = (const float*)d_in[4];
  const float* adst1  = (const float*)d_in[5];
  const float* b1     = (const float*)d_in[6];
  const float* W2     = (const float*)d_in[7];
  const float* asrc2  = (const float*)d_in[8];
  const float* adst2  = (const float*)d_in[9];
  const float* b2     = (const float*)d_in[10];
  const float* W3     = (const float*)d_in[11];
  const float* asrc3  = (const float*)d_in[12];
  const float* adst3  = (const float*)d_in[13];
  const float* b3     = (const float*)d_in[14];
  const float* lnW    = (const float*)d_in[15];
  const float* lnb    = (const float*)d_in[16];
  const float* l0W    = (const float*)d_in[17];
  const float* l0b    = (const float*)d_in[18];
  const float* l1W    = (const float*)d_in[19];
  const float* l1b    = (const float*)d_in[20];
  float* outp = (float*)d_out;

  const int N = in_sizes[2];
  const int E = in_sizes[1] / 2;
  const int Etot = E + N;
  const int G = out_size;
  const int B = (N + 255) / 256;  // real buckets (<= BPAD)

  const int* src_e = adj;
  const int* dst_e = adj + E;

  uintptr_t p = (uintptr_t)d_ws;
  auto alloc = [&](size_t bytes) -> void* {
    void* r = (void*)p;
    p += (bytes + 255) & ~(size_t)255;
    return r;
  };
  int*      hist      = (int*)alloc((size_t)BPAD * NBLK * 4);
  int*      row_start = (int*)alloc((size_t)(N + 1) * 4);
  int*      csr_src   = (int*)alloc((size_t)Etot * 4);
  unsigned int* ebuf  = (unsigned int*)alloc((size_t)E * 4);
  __half2*  hbufL     = (__half2*)alloc((size_t)N * 32 * 4);   // lin output (h)
  _Float16* hbufA     = (_Float16*)alloc((size_t)N * 64 * 2);  // agg output
  float*    as_       = (float*)alloc((size_t)N * 4);
  float*    ad_       = (float*)alloc((size_t)N * 4);
  float*    pool      = (float*)alloc((size_t)G * 64 * 4);
  int*      root      = (int*)alloc((size_t)G * 4);

  int chunk = (E + NBLK - 1) / NBLK;
  hist_kernel<<<dim3(NBLK), dim3(256), 0, stream>>>(dst_e, hist, E, chunk, pool, root, G);
  hscan_kernel<<<dim3(1), dim3(256), 0, stream>>>(hist);
  scatter_kernel<<<dim3(NBLK), dim3(256), 0, stream>>>(src_e, dst_e, hist, ebuf, E, chunk);
  build_kernel<<<dim3(B), dim3(256), 0, stream>>>(ebuf, hist, row_start, csr_src, N, E);

  const int aggGrid = (N + 31) / 32;
  const int nwaves = LINBLK * 4;

  // layer 1
  lin_attn_kernel<128, float><<<dim3(LINBLK), dim3(256), 0, stream>>>(
      x, W1, asrc1, adst1, hbufL, as_, ad_, N, nwaves);
  agg_kernel<<<dim3(aggGrid), dim3(256), 0, stream>>>(hbufL, as_, ad_, csr_src, row_start, b1, hbufA, N);
  // layer 2
  lin_attn_kernel<64, _Float16><<<dim3(LINBLK), dim3(256), 0, stream>>>(
      hbufA, W2, asrc2, adst2, hbufL, as_, ad_, N, nwaves);
  agg_kernel<<<dim3(aggGrid), dim3(256), 0, stream>>>(hbufL, as_, ad_, csr_src, row_start, b2, hbufA, N);
  // layer 3
  lin_attn_kernel<64, _Float16><<<dim3(LINBLK), dim3(256), 0, stream>>>(
      hbufA, W3, asrc3, adst3, hbufL, as_, ad_, N, nwaves);
  agg_kernel<<<dim3(aggGrid), dim3(256), 0, stream>>>(hbufL, as_, ad_, csr_src, row_start, b3, hbufA, N);

  // pool + root
  const int ROWS = 2048;
  int pchunk = (N + ROWS - 1) / ROWS;
  pool_kernel<<<dim3(ROWS / 4), dim3(256), 0, stream>>>(hbufA, batch, pool, root, N, pchunk);

  // head
  final_kernel<<<dim3((G + 3) / 4), dim3(256), 0, stream>>>(
      pool, root, x, l0W, l0b, lnW, lnb, l1W, l1b, outp, G, N);
}